// Round 2
// baseline (135.933 us; speedup 1.0000x reference)
//
#include <hip/hip_runtime.h>
#include <hip/hip_bf16.h>

#define HW 16384   // 128*128
#define CC 64
#define BB 4

typedef __attribute__((ext_vector_type(8))) short bf8;   // 8 bf16 (4 VGPRs)
typedef __attribute__((ext_vector_type(4))) float f4;    // MFMA C/D frag

static __device__ __forceinline__ float bf2f(unsigned short u) {
    return __uint_as_float(((unsigned)u) << 16);
}
static __device__ __forceinline__ unsigned short f2bf(float f) {
    __hip_bfloat16 h = __float2bfloat16(f);   // RNE
    return *reinterpret_cast<unsigned short*>(&h);
}

// ---------------------------------------------------------------------------
// K0: weight repack (blocks 0..215) + x transpose via LDS (blocks 216..1239).
//  wA   [32][576] bf16 : wA[m][t*64+c] = w_off[m][c][t]   (rows 27..31 zero)
//  Wal2 : wave-coalesced A-frag layout for k_fused (NO LDS staging needed):
//         chunk g = (tap*2+h2)*4+mt, lane l: Wal2[(g*64+l)*8 + j] =
//         w_align[o=mt*16+(l&15)][c=h2*32+(l>>4)*8+j][tap]  (as bf16)
//         -> each (tap,h2,mt) A-frag is ONE fully-coalesced 1KB wave load.
//  xT  [b*HW+hw][c]   : channels contiguous (128B rows)
// ---------------------------------------------------------------------------
__global__ __launch_bounds__(256) void k_prep_tx(const float* __restrict__ x,
                                                 const float* __restrict__ w_off,
                                                 const float* __restrict__ w_align,
                                                 unsigned short* __restrict__ xT,
                                                 unsigned short* __restrict__ wA,
                                                 unsigned short* __restrict__ Wal2) {
    __shared__ unsigned T32[64 * 33];   // 8448 B
    int bx = blockIdx.x, t = threadIdx.x;
    if (bx < 216) {
        int i = bx * 256 + t;
        if (i < 32 * 576) {
            int m = i / 576, r = i - m * 576, tt = r >> 6, c = r & 63;
            float v = (m < 27) ? w_off[m * 576 + c * 9 + tt] : 0.f;
            wA[i] = f2bf(v);
        } else {
            int j = i - 32 * 576;           // 0..36863 = 72 groups x 64 lanes x 8
            int jj = j & 7;
            int chunk = j >> 3;
            int l = chunk & 63;
            int g = chunk >> 6;             // (tap*2+h2)*4 + mt
            int mt = g & 3;
            int th = g >> 2;
            int h2 = th & 1;
            int tp = th >> 1;               // tap 0..8
            int o = mt * 16 + (l & 15);
            int c = h2 * 32 + (l >> 4) * 8 + jj;
            Wal2[j] = f2bf(w_align[o * 576 + c * 9 + tp]);
        }
        return;
    }
    int pix0 = (bx - 216) * 64;
    int b = pix0 >> 14, hw0 = pix0 & (HW - 1);
    const float* xb = x + (size_t)b * CC * HW + hw0;
#pragma unroll
    for (int u = 0; u < 8; u++) {
        int i = t + 256 * u;                 // 2048 = 32 cp x 64 p
        int cp = i >> 6, p = i & 63;
        float v0 = xb[(size_t)(2 * cp) * HW + p];
        float v1 = xb[(size_t)(2 * cp + 1) * HW + p];
        T32[p * 33 + cp] = (unsigned)f2bf(v0) | ((unsigned)f2bf(v1) << 16);
    }
    __syncthreads();
#pragma unroll
    for (int u = 0; u < 2; u++) {
        int i = t + 256 * u;                 // 512 = 64 p x 8 q
        int p = i >> 3, q = i & 7;
        uint4 qq;
        qq.x = T32[p * 33 + q * 4 + 0];
        qq.y = T32[p * 33 + q * 4 + 1];
        qq.z = T32[p * 33 + q * 4 + 2];
        qq.w = T32[p * 33 + q * 4 + 3];
        *(uint4*)(xT + ((size_t)b * HW + hw0 + p) * CC + q * 8) = qq;
    }
}

// ---------------------------------------------------------------------------
// K1: offset conv, 9-tap shifted MFMA GEMM. Weights staged ONCE in LDS
// (rows padded 576->584 bf16: bank (4(col+quad))%32, <=2-way = free).
// Barrier-free tap loop; wave = 16 px, 32 outputs (27 used).
// ---------------------------------------------------------------------------
__global__ __launch_bounds__(256, 4) void k_conv(const unsigned short* __restrict__ xT,
                                                 const unsigned short* __restrict__ wA,
                                                 const float* __restrict__ b_off,
                                                 float* __restrict__ off) {
    __shared__ __align__(16) unsigned short WL[32 * 584];   // 37376 B
    int t = threadIdx.x, lane = t & 63, wv = t >> 6;
    int quad = lane >> 4, col = lane & 15;
#pragma unroll
    for (int u = 0; u < 9; u++) {
        int idx = t + 256 * u;               // 2304 = 32 rows x 72 uint4
        int row = idx / 72, jb = idx - row * 72;
        *(uint4*)(WL + row * 584 + jb * 8) = ((const uint4*)wA)[idx];
    }
    __syncthreads();

    int n = blockIdx.x * 64 + wv * 16 + col;           // global pixel
    int b = n >> 14, hw = n & (HW - 1), h = hw >> 7, w = hw & 127;
    const unsigned short* xTb = xT + (size_t)b * HW * CC;
    const bf8 zero = {0, 0, 0, 0, 0, 0, 0, 0};

    f4 acc0 = {0.f, 0.f, 0.f, 0.f};
    f4 acc1 = {0.f, 0.f, 0.f, 0.f};
#pragma unroll
    for (int tap = 0; tap < 9; tap++) {
        int dyt = tap / 3 - 1, dxt = tap - (tap / 3) * 3 - 1;
        int hs = h + dyt, ws = w + dxt;
        bool valid = ((unsigned)hs < 128u) && ((unsigned)ws < 128u);
        int hc = min(max(hs, 0), 127), wc = min(max(ws, 0), 127);
        const unsigned short* src = xTb + ((size_t)(hc * 128 + wc)) * CC + quad * 8;
        bf8 b0 = *(const bf8*)(src);
        bf8 b1 = *(const bf8*)(src + 32);
        b0 = valid ? b0 : zero;
        b1 = valid ? b1 : zero;
        const unsigned short* l0 = WL + col * 584 + tap * 64 + quad * 8;
        const unsigned short* l1 = WL + (col + 16) * 584 + tap * 64 + quad * 8;
        acc0 = __builtin_amdgcn_mfma_f32_16x16x32_bf16(*(const bf8*)l0, b0, acc0, 0, 0, 0);
        acc1 = __builtin_amdgcn_mfma_f32_16x16x32_bf16(*(const bf8*)l1, b0, acc1, 0, 0, 0);
        acc0 = __builtin_amdgcn_mfma_f32_16x16x32_bf16(*(const bf8*)(l0 + 32), b1, acc0, 0, 0, 0);
        acc1 = __builtin_amdgcn_mfma_f32_16x16x32_bf16(*(const bf8*)(l1 + 32), b1, acc1, 0, 0, 0);
    }
#pragma unroll
    for (int i = 0; i < 4; i++) {
        int o0 = quad * 4 + i;                          // 0..15, always < 27
        {
            float v = acc0[i] + b_off[o0];
            if (o0 >= 18) v = 2.f / (1.f + __expf(-v));
            off[((size_t)b * 27 + o0) * HW + hw] = v;
        }
        int o1 = 16 + o0;
        if (o1 < 27) {
            float v = acc1[i] + b_off[o1];
            if (o1 >= 18) v = 2.f / (1.f + __expf(-v));
            off[((size_t)b * 27 + o1) * HW + hw] = v;
        }
    }
}

// ---------------------------------------------------------------------------
// K2 (fused), v3: ZERO LDS, ZERO barriers. A-frags are read straight from
// the wave-coalesced Wal2 layout (one 1KB coalesced wave load per
// (tap,h2,mt)); they feed only MFMA operands whose results aren't consumed
// until the epilogue, so weight-load latency is off the critical path.
// With no barriers the 9 unrolled taps form one big independent-load DAG:
// the compiler software-pipelines tap k+1's gathers under tap k's bilinear.
// All waves fully independent -> no lockstep stalls.
// ---------------------------------------------------------------------------
__global__ __launch_bounds__(256, 4) void k_fused(const unsigned short* __restrict__ xT,
                                                  const float* __restrict__ off,
                                                  const unsigned short* __restrict__ Wal2,
                                                  const float* __restrict__ b_align,
                                                  float* __restrict__ wten) {
    int t = threadIdx.x, lane = t & 63, wv = t >> 6;
    int quad = lane >> 4, col = lane & 15;
    int pix0 = blockIdx.x * 64;
    int b = pix0 >> 14;
    int px = (pix0 & (HW - 1)) + wv * 16 + col;        // lane's pixel (within b)
    int h = px >> 7, w = px & 127;
    const unsigned short* xTb = xT + (size_t)b * HW * CC;
    const float* offp = off + (size_t)b * 27 * HW + px;
    const unsigned short* wl = Wal2 + lane * 8;        // + group*512 shorts

    // hoist ALL offsets/masks: 27 independent coalesced loads, issued once
    float dyv[9], dxv[9], mv[9];
#pragma unroll
    for (int k = 0; k < 9; k++) {
        dyv[k] = offp[(size_t)(2 * k) * HW];
        dxv[k] = offp[(size_t)(2 * k + 1) * HW];
        mv[k]  = offp[(size_t)(18 + k) * HW];
    }

    f4 acc[4];
#pragma unroll
    for (int mt = 0; mt < 4; mt++) acc[mt] = (f4){0.f, 0.f, 0.f, 0.f};

#pragma unroll
    for (int k = 0; k < 9; k++) {
        float dy = dyv[k], dx = dxv[k], m = mv[k];
        int k3 = k / 3;
        float ys = (float)(h + k3 - 1) + dy;
        float xs = (float)(w + (k - 3 * k3) - 1) + dx;
        float y0f = floorf(ys), x0f = floorf(xs);
        float fy = ys - y0f, fx = xs - x0f;
        int y0 = (int)y0f, x0 = (int)x0f;
        int y1 = y0 + 1, x1 = x0 + 1;
        bool vy0 = (unsigned)y0 < 128u, vy1 = (unsigned)y1 < 128u;
        bool vx0 = (unsigned)x0 < 128u, vx1 = (unsigned)x1 < 128u;
        int cy0 = min(max(y0, 0), 127), cy1 = min(max(y1, 0), 127);
        int cx0 = min(max(x0, 0), 127), cx1 = min(max(x1, 0), 127);
        float w00 = (1.f - fy) * (1.f - fx) * ((vy0 && vx0) ? m : 0.f);
        float w01 = (1.f - fy) * fx         * ((vy0 && vx1) ? m : 0.f);
        float w10 = fy * (1.f - fx)         * ((vy1 && vx0) ? m : 0.f);
        float w11 = fy * fx                 * ((vy1 && vx1) ? m : 0.f);

        const unsigned short* c00 = xTb + ((size_t)(cy0 * 128 + cx0)) * CC + quad * 8;
        const unsigned short* c01 = xTb + ((size_t)(cy0 * 128 + cx1)) * CC + quad * 8;
        const unsigned short* c10 = xTb + ((size_t)(cy1 * 128 + cx0)) * CC + quad * 8;
        const unsigned short* c11 = xTb + ((size_t)(cy1 * 128 + cx1)) * CC + quad * 8;
        // 8 independent 16B gathers (2 halves x 4 corners)
        uint4 qa0 = *(const uint4*)(c00),      qa1 = *(const uint4*)(c01);
        uint4 qa2 = *(const uint4*)(c10),      qa3 = *(const uint4*)(c11);
        uint4 qb0 = *(const uint4*)(c00 + 32), qb1 = *(const uint4*)(c01 + 32);
        uint4 qb2 = *(const uint4*)(c10 + 32), qb3 = *(const uint4*)(c11 + 32);

        bf8 bfrag[2];
#pragma unroll
        for (int h2 = 0; h2 < 2; h2++) {
            const unsigned short* u00 = (const unsigned short*)(h2 ? &qb0 : &qa0);
            const unsigned short* u01 = (const unsigned short*)(h2 ? &qb1 : &qa1);
            const unsigned short* u10 = (const unsigned short*)(h2 ? &qb2 : &qa2);
            const unsigned short* u11 = (const unsigned short*)(h2 ? &qb3 : &qa3);
            unsigned short ov[8];
#pragma unroll
            for (int j = 0; j < 8; j++) {
                float v = w00 * bf2f(u00[j]) + w01 * bf2f(u01[j])
                        + w10 * bf2f(u10[j]) + w11 * bf2f(u11[j]);
                ov[j] = f2bf(v);
            }
            bfrag[h2] = *(const bf8*)ov;
        }
#pragma unroll
        for (int h2 = 0; h2 < 2; h2++) {
#pragma unroll
            for (int mt = 0; mt < 4; mt++) {
                const bf8 a = *(const bf8*)(wl + (size_t)(((k * 2 + h2) * 4 + mt) * 512));
                acc[mt] = __builtin_amdgcn_mfma_f32_16x16x32_bf16(a, bfrag[h2], acc[mt], 0, 0, 0);
            }
        }
    }

    // ---- epilogue: bias + exp(sigmoid) ----
    float* wb = wten + (size_t)b * CC * HW + px;
#pragma unroll
    for (int mt = 0; mt < 4; mt++)
#pragma unroll
        for (int i = 0; i < 4; i++) {
            int o = mt * 16 + quad * 4 + i;
            float u = acc[mt][i] + b_align[o];
            float sg = 1.f / (1.f + __expf(-u));
            wb[(size_t)o * HW] = __expf(sg);
        }
}

// ---------------------------------------------------------------------------
// K3: out = pool3s2(w*x)/pool3s2(w) (the /9 cancels; zero-pad taps drop out).
// ---------------------------------------------------------------------------
__global__ __launch_bounds__(256) void k_pool(const float* __restrict__ x,
                                              const float* __restrict__ wten,
                                              float* __restrict__ out) {
    int idx = blockIdx.x * 256 + threadIdx.x;
    int ow = idx & 63;
    int oh = (idx >> 6) & 63;
    int bc = idx >> 12;
    const float* wp = wten + (size_t)bc * HW;
    const float* xp = x + (size_t)bc * HW;
    float num = 0.f, den = 0.f;
#pragma unroll
    for (int iy = 0; iy < 3; iy++) {
        int y = 2 * oh + iy - 1;
        if ((unsigned)y >= 128u) continue;
#pragma unroll
        for (int ix = 0; ix < 3; ix++) {
            int xc = 2 * ow + ix - 1;
            if ((unsigned)xc >= 128u) continue;
            float wv = wp[y * 128 + xc];
            float xv = xp[y * 128 + xc];
            num = fmaf(wv, xv, num);
            den += wv;
        }
    }
    out[idx] = num / den;
}

// ---------------------------------------------------------------------------
extern "C" void kernel_launch(void* const* d_in, const int* in_sizes, int n_in,
                              void* d_out, int out_size, void* d_ws, size_t ws_size,
                              hipStream_t stream) {
    const float* x       = (const float*)d_in[0];
    const float* w_off   = (const float*)d_in[1];
    const float* b_off   = (const float*)d_in[2];
    const float* w_align = (const float*)d_in[3];
    const float* b_align = (const float*)d_in[4];
    float* out = (float*)d_out;

    // workspace layout (~32.4 MB):
    char* p = (char*)d_ws;
    float* off  = (float*)p;                  p += (size_t)BB * 27 * HW * 4;  // 7.08 MB
    float* wten = (float*)p;                  p += (size_t)BB * CC * HW * 4;  // 16.78 MB
    unsigned short* xT  = (unsigned short*)p; p += (size_t)BB * HW * CC * 2;  // 8.39 MB
    unsigned short* wA  = (unsigned short*)p; p += 32 * 576 * 2;              // 36.9 KB
    unsigned short* Wal2 = (unsigned short*)p;                                // 73.7 KB

    k_prep_tx<<<dim3(1240), dim3(256), 0, stream>>>(x, w_off, w_align, xT, wA, Wal2);
    k_conv<<<dim3(1024), dim3(256), 0, stream>>>(xT, wA, b_off, off);
    k_fused<<<dim3(1024), dim3(256), 0, stream>>>(xT, off, Wal2, b_align, wten);
    k_pool<<<dim3(4096), dim3(256), 0, stream>>>(x, wten, out);
}

// Round 3
// 117.037 us; speedup vs baseline: 1.1615x; 1.1615x over previous
//
#include <hip/hip_runtime.h>
#include <hip/hip_bf16.h>

#define HW 16384   // 128*128
#define CC 64
#define BB 4

typedef __attribute__((ext_vector_type(8))) short bf8;   // 8 bf16 (4 VGPRs)
typedef __attribute__((ext_vector_type(4))) float f4;    // MFMA C/D frag

static __device__ __forceinline__ float bf2f(unsigned short u) {
    return __uint_as_float(((unsigned)u) << 16);
}
static __device__ __forceinline__ unsigned short f2bf(float f) {
    __hip_bfloat16 h = __float2bfloat16(f);   // RNE
    return *reinterpret_cast<unsigned short*>(&h);
}

// ---------------------------------------------------------------------------
// K0: weight repack (blocks 0..215) + x transpose via LDS (blocks 216..1239).
//  wA2 : wave-coalesced A-frags for k_conv. group g = tap*4 + h2*2 + m2,
//        lane l: wA2[(g*64+l)*8+j] = w_off[m2*16+(l&15)][h2*32+(l>>4)*8+j][tap]
//        (rows >=27 zero). 36,864 B.
//  Wal2: wave-coalesced A-frags for k_fused. g = (tap*2+h2)*4+mt:
//        Wal2[(g*64+l)*8+j] = w_align[mt*16+(l&15)][h2*32+(l>>4)*8+j][tap]
//  xT  [b*HW+hw][c] : channels contiguous (128B rows)
// ---------------------------------------------------------------------------
__global__ __launch_bounds__(256) void k_prep_tx(const float* __restrict__ x,
                                                 const float* __restrict__ w_off,
                                                 const float* __restrict__ w_align,
                                                 unsigned short* __restrict__ xT,
                                                 unsigned short* __restrict__ wA2,
                                                 unsigned short* __restrict__ Wal2) {
    __shared__ unsigned T32[64 * 33];   // 8448 B
    int bx = blockIdx.x, t = threadIdx.x;
    if (bx < 216) {
        int i = bx * 256 + t;
        if (i < 32 * 576) {             // 18432 elems -> wA2
            int jj = i & 7;
            int chunk = i >> 3;
            int l = chunk & 63;
            int g = chunk >> 6;         // 0..35 = tap*4 + h2*2 + m2
            int m2 = g & 1;
            int h2 = (g >> 1) & 1;
            int tp = g >> 2;            // tap 0..8
            int m = m2 * 16 + (l & 15);
            int c = h2 * 32 + (l >> 4) * 8 + jj;
            float v = (m < 27) ? w_off[m * 576 + c * 9 + tp] : 0.f;
            wA2[i] = f2bf(v);
        } else {
            int j = i - 32 * 576;       // 0..36863 = 72 groups x 64 lanes x 8
            int jj = j & 7;
            int chunk = j >> 3;
            int l = chunk & 63;
            int g = chunk >> 6;         // (tap*2+h2)*4 + mt
            int mt = g & 3;
            int th = g >> 2;
            int h2 = th & 1;
            int tp = th >> 1;           // tap 0..8
            int o = mt * 16 + (l & 15);
            int c = h2 * 32 + (l >> 4) * 8 + jj;
            Wal2[j] = f2bf(w_align[o * 576 + c * 9 + tp]);
        }
        return;
    }
    int pix0 = (bx - 216) * 64;
    int b = pix0 >> 14, hw0 = pix0 & (HW - 1);
    const float* xb = x + (size_t)b * CC * HW + hw0;
#pragma unroll
    for (int u = 0; u < 8; u++) {
        int i = t + 256 * u;                 // 2048 = 32 cp x 64 p
        int cp = i >> 6, p = i & 63;
        float v0 = xb[(size_t)(2 * cp) * HW + p];
        float v1 = xb[(size_t)(2 * cp + 1) * HW + p];
        T32[p * 33 + cp] = (unsigned)f2bf(v0) | ((unsigned)f2bf(v1) << 16);
    }
    __syncthreads();
#pragma unroll
    for (int u = 0; u < 2; u++) {
        int i = t + 256 * u;                 // 512 = 64 p x 8 q
        int p = i >> 3, q = i & 7;
        uint4 qq;
        qq.x = T32[p * 33 + q * 4 + 0];
        qq.y = T32[p * 33 + q * 4 + 1];
        qq.z = T32[p * 33 + q * 4 + 2];
        qq.w = T32[p * 33 + q * 4 + 3];
        *(uint4*)(xT + ((size_t)b * HW + hw0 + p) * CC + q * 8) = qq;
    }
}

// ---------------------------------------------------------------------------
// K1 (v4): offset conv. The block's 9 fixed taps all live in a 3x66 spatial
// tile (rows clamp(h-1..h+1), cols clamp(w0-1..w0+64)) staged ONCE in LDS
// (25,344 B -> grid-limited 4 blocks/CU all resident). Chunk-XOR swizzle
// (slot s holds global chunk s^(e&7)) -> conflict-free ds_read_b128 with
// per-lane e. Taps are always in-tile (clamping commutes). Weights via
// wave-coalesced VMEM loads (wA2): one barrier total, no LDS weight stage.
// ---------------------------------------------------------------------------
__global__ __launch_bounds__(256, 4) void k_conv(const unsigned short* __restrict__ xT,
                                                 const unsigned short* __restrict__ wA2,
                                                 const float* __restrict__ b_off,
                                                 float* __restrict__ off) {
    __shared__ __align__(16) unsigned short TC[198 * 64];   // 3*66 entries * 128B
    int t = threadIdx.x, lane = t & 63, wv = t >> 6;
    int quad = lane >> 4, col = lane & 15;
    int n0 = blockIdx.x * 64;
    int b = n0 >> 14, hw0 = n0 & (HW - 1);
    int h = hw0 >> 7, w0 = hw0 & 127;
    int pxo = wv * 16 + col;
    int hw = hw0 + pxo, w = w0 + pxo;
    const unsigned short* xTb = xT + (size_t)b * HW * CC;

    // stage 3x66 tile: 1584 16B chunks; source chunk pre-swizzled (G21)
#pragma unroll
    for (int u = 0; u < 7; u++) {
        int i = t + 256 * u;
        if (i < 1584) {
            int e = i >> 3, s = i & 7;
            int ty = e / 66, tx = e - ty * 66;
            int gy = min(max(h - 1 + ty, 0), 127);
            int gx = min(max(w0 - 1 + tx, 0), 127);
            int c = s ^ (e & 7);
            uint4 q = *(const uint4*)(xTb + ((size_t)((gy << 7) + gx)) * CC + c * 8);
            *(uint4*)(TC + i * 8) = q;
        }
    }
    __syncthreads();

    const bf8 zero = {0, 0, 0, 0, 0, 0, 0, 0};
    f4 acc0 = {0.f, 0.f, 0.f, 0.f};
    f4 acc1 = {0.f, 0.f, 0.f, 0.f};
#pragma unroll
    for (int tap = 0; tap < 9; tap++) {
        int dyt = tap / 3 - 1, dxt = tap - (tap / 3) * 3 - 1;
        int hs = h + dyt, ws = w + dxt;
        bool valid = ((unsigned)hs < 128u) && ((unsigned)ws < 128u);
        int e = (dyt + 1) * 66 + pxo + dxt + 1;       // always in tile
        int sL = quad ^ (e & 7);
        bf8 b0 = *(const bf8*)(TC + e * 64 + (sL << 3));
        bf8 b1 = *(const bf8*)(TC + e * 64 + ((sL ^ 4) << 3));
        b0 = valid ? b0 : zero;
        b1 = valid ? b1 : zero;
        const bf8 a00 = *(const bf8*)(wA2 + (((tap * 4 + 0) * 64 + lane) << 3));
        const bf8 a01 = *(const bf8*)(wA2 + (((tap * 4 + 1) * 64 + lane) << 3));
        const bf8 a10 = *(const bf8*)(wA2 + (((tap * 4 + 2) * 64 + lane) << 3));
        const bf8 a11 = *(const bf8*)(wA2 + (((tap * 4 + 3) * 64 + lane) << 3));
        acc0 = __builtin_amdgcn_mfma_f32_16x16x32_bf16(a00, b0, acc0, 0, 0, 0);
        acc1 = __builtin_amdgcn_mfma_f32_16x16x32_bf16(a01, b0, acc1, 0, 0, 0);
        acc0 = __builtin_amdgcn_mfma_f32_16x16x32_bf16(a10, b1, acc0, 0, 0, 0);
        acc1 = __builtin_amdgcn_mfma_f32_16x16x32_bf16(a11, b1, acc1, 0, 0, 0);
    }
#pragma unroll
    for (int i = 0; i < 4; i++) {
        int o0 = quad * 4 + i;                          // 0..15, always < 27
        {
            float v = acc0[i] + b_off[o0];
            if (o0 >= 18) v = 2.f / (1.f + __expf(-v));
            off[((size_t)b * 27 + o0) * HW + hw] = v;
        }
        int o1 = 16 + o0;
        if (o1 < 27) {
            float v = acc1[i] + b_off[o1];
            if (o1 >= 18) v = 2.f / (1.f + __expf(-v));
            off[((size_t)b * 27 + o1) * HW + hw] = v;
        }
    }
}

// ---------------------------------------------------------------------------
// K2 (fused), v4: bilinear corners served from an LDS spatial tile.
// Offsets are small (sigma~0.5): the block's 64 px x 9 taps x 4 corners land
// in rows [h-2,h+3] x cols [w0-3,w0+66] with prob ~98%+ per tap. Stage that
// 6x70 tile (53,760 B, chunk-XOR swizzled) once; gathers become
// conflict-free ds_read_b128 on the LDS pipe instead of all-miss L1 loads
// (the R2-identified MSHR/miss-throughput bound). Rare out-of-tile corners
// take an exec-masked global fallback -- bit-identical values.
// 3 blocks/CU (LDS 161,280/163,840). Weights via Wal2 VMEM (now uncontended).
// ---------------------------------------------------------------------------
__global__ __launch_bounds__(256, 3) void k_fused(const unsigned short* __restrict__ xT,
                                                  const float* __restrict__ off,
                                                  const unsigned short* __restrict__ Wal2,
                                                  const float* __restrict__ b_align,
                                                  float* __restrict__ wten) {
    __shared__ __align__(16) unsigned short TF[420 * 64];   // 6*70 entries * 128B

    int t = threadIdx.x, lane = t & 63, wv = t >> 6;
    int quad = lane >> 4, col = lane & 15;
    int pix0 = blockIdx.x * 64;
    int b = pix0 >> 14, hw0 = pix0 & (HW - 1);
    int h = hw0 >> 7, w0 = hw0 & 127;
    int pxo = wv * 16 + col;
    int px = hw0 + pxo, w = w0 + pxo;
    const unsigned short* xTb = xT + (size_t)b * HW * CC;
    const float* offp = off + (size_t)b * 27 * HW + px;
    const unsigned short* wl = Wal2 + lane * 8;        // + group*512 shorts

    // hoist ALL offsets/masks: 27 independent coalesced loads, issued once
    float dyv[9], dxv[9], mv[9];
#pragma unroll
    for (int k = 0; k < 9; k++) {
        dyv[k] = offp[(size_t)(2 * k) * HW];
        dxv[k] = offp[(size_t)(2 * k + 1) * HW];
        mv[k]  = offp[(size_t)(18 + k) * HW];
    }

    // stage 6x70 tile: 3360 16B chunks; source chunk pre-swizzled (G21)
#pragma unroll
    for (int u = 0; u < 14; u++) {
        int i = t + 256 * u;
        if (i < 3360) {
            int e = i >> 3, s = i & 7;
            int ty = e / 70, tx = e - ty * 70;
            int gy = min(max(h - 2 + ty, 0), 127);
            int gx = min(max(w0 - 3 + tx, 0), 127);
            int c = s ^ (e & 7);
            uint4 q = *(const uint4*)(xTb + ((size_t)((gy << 7) + gx)) * CC + c * 8);
            *(uint4*)(TF + i * 8) = q;
        }
    }
    __syncthreads();

    int hm2 = h - 2, hp3 = h + 3, wm3 = w0 - 3, wp66 = w0 + 66;

    f4 acc[4];
#pragma unroll
    for (int mt = 0; mt < 4; mt++) acc[mt] = (f4){0.f, 0.f, 0.f, 0.f};

#pragma unroll
    for (int k = 0; k < 9; k++) {
        float dy = dyv[k], dx = dxv[k], m = mv[k];
        int k3 = k / 3;
        float ys = (float)(h + k3 - 1) + dy;
        float xs = (float)(w + (k - 3 * k3) - 1) + dx;
        float y0f = floorf(ys), x0f = floorf(xs);
        float fy = ys - y0f, fx = xs - x0f;
        int y0 = (int)y0f, x0 = (int)x0f;
        int y1 = y0 + 1, x1 = x0 + 1;
        bool vy0 = (unsigned)y0 < 128u, vy1 = (unsigned)y1 < 128u;
        bool vx0 = (unsigned)x0 < 128u, vx1 = (unsigned)x1 < 128u;
        int cy0 = min(max(y0, 0), 127), cy1 = min(max(y1, 0), 127);
        int cx0 = min(max(x0, 0), 127), cx1 = min(max(x1, 0), 127);
        float w00 = (1.f - fy) * (1.f - fx) * ((vy0 && vx0) ? m : 0.f);
        float w01 = (1.f - fy) * fx         * ((vy0 && vx1) ? m : 0.f);
        float w10 = fy * (1.f - fx)         * ((vy1 && vx0) ? m : 0.f);
        float w11 = fy * fx                 * ((vy1 && vx1) ? m : 0.f);

        bool inT = (cy0 >= hm2) & (cy1 <= hp3) & (cx0 >= wm3) & (cx1 <= wp66);
        uint4 qa0, qa1, qa2, qa3, qb0, qb1, qb2, qb3;
        if (inT) {
            int r0 = (cy0 - hm2) * 70 - wm3, r1 = (cy1 - hm2) * 70 - wm3;
            int e00 = r0 + cx0, e01 = r0 + cx1, e10 = r1 + cx0, e11 = r1 + cx1;
            int s00 = quad ^ (e00 & 7), s01 = quad ^ (e01 & 7);
            int s10 = quad ^ (e10 & 7), s11 = quad ^ (e11 & 7);
            qa0 = *(const uint4*)(TF + e00 * 64 + (s00 << 3));
            qa1 = *(const uint4*)(TF + e01 * 64 + (s01 << 3));
            qa2 = *(const uint4*)(TF + e10 * 64 + (s10 << 3));
            qa3 = *(const uint4*)(TF + e11 * 64 + (s11 << 3));
            qb0 = *(const uint4*)(TF + e00 * 64 + ((s00 ^ 4) << 3));
            qb1 = *(const uint4*)(TF + e01 * 64 + ((s01 ^ 4) << 3));
            qb2 = *(const uint4*)(TF + e10 * 64 + ((s10 ^ 4) << 3));
            qb3 = *(const uint4*)(TF + e11 * 64 + ((s11 ^ 4) << 3));
        } else {
            const unsigned short* c00 = xTb + ((size_t)(cy0 * 128 + cx0)) * CC + quad * 8;
            const unsigned short* c01 = xTb + ((size_t)(cy0 * 128 + cx1)) * CC + quad * 8;
            const unsigned short* c10 = xTb + ((size_t)(cy1 * 128 + cx0)) * CC + quad * 8;
            const unsigned short* c11 = xTb + ((size_t)(cy1 * 128 + cx1)) * CC + quad * 8;
            qa0 = *(const uint4*)(c00);      qa1 = *(const uint4*)(c01);
            qa2 = *(const uint4*)(c10);      qa3 = *(const uint4*)(c11);
            qb0 = *(const uint4*)(c00 + 32); qb1 = *(const uint4*)(c01 + 32);
            qb2 = *(const uint4*)(c10 + 32); qb3 = *(const uint4*)(c11 + 32);
        }

        bf8 bfrag[2];
#pragma unroll
        for (int h2 = 0; h2 < 2; h2++) {
            const unsigned short* u00 = (const unsigned short*)(h2 ? &qb0 : &qa0);
            const unsigned short* u01 = (const unsigned short*)(h2 ? &qb1 : &qa1);
            const unsigned short* u10 = (const unsigned short*)(h2 ? &qb2 : &qa2);
            const unsigned short* u11 = (const unsigned short*)(h2 ? &qb3 : &qa3);
            unsigned short ov[8];
#pragma unroll
            for (int j = 0; j < 8; j++) {
                float v = w00 * bf2f(u00[j]) + w01 * bf2f(u01[j])
                        + w10 * bf2f(u10[j]) + w11 * bf2f(u11[j]);
                ov[j] = f2bf(v);
            }
            bfrag[h2] = *(const bf8*)ov;
        }
#pragma unroll
        for (int h2 = 0; h2 < 2; h2++) {
#pragma unroll
            for (int mt = 0; mt < 4; mt++) {
                const bf8 a = *(const bf8*)(wl + (size_t)(((k * 2 + h2) * 4 + mt) * 512));
                acc[mt] = __builtin_amdgcn_mfma_f32_16x16x32_bf16(a, bfrag[h2], acc[mt], 0, 0, 0);
            }
        }
    }

    // ---- epilogue: bias + exp(sigmoid) ----
    float* wb = wten + (size_t)b * CC * HW + px;
#pragma unroll
    for (int mt = 0; mt < 4; mt++)
#pragma unroll
        for (int i = 0; i < 4; i++) {
            int o = mt * 16 + quad * 4 + i;
            float u = acc[mt][i] + b_align[o];
            float sg = 1.f / (1.f + __expf(-u));
            wb[(size_t)o * HW] = __expf(sg);
        }
}

// ---------------------------------------------------------------------------
// K3: out = pool3s2(w*x)/pool3s2(w) (the /9 cancels; zero-pad taps drop out).
// ---------------------------------------------------------------------------
__global__ __launch_bounds__(256) void k_pool(const float* __restrict__ x,
                                              const float* __restrict__ wten,
                                              float* __restrict__ out) {
    int idx = blockIdx.x * 256 + threadIdx.x;
    int ow = idx & 63;
    int oh = (idx >> 6) & 63;
    int bc = idx >> 12;
    const float* wp = wten + (size_t)bc * HW;
    const float* xp = x + (size_t)bc * HW;
    float num = 0.f, den = 0.f;
#pragma unroll
    for (int iy = 0; iy < 3; iy++) {
        int y = 2 * oh + iy - 1;
        if ((unsigned)y >= 128u) continue;
#pragma unroll
        for (int ix = 0; ix < 3; ix++) {
            int xc = 2 * ow + ix - 1;
            if ((unsigned)xc >= 128u) continue;
            float wv = wp[y * 128 + xc];
            float xv = xp[y * 128 + xc];
            num = fmaf(wv, xv, num);
            den += wv;
        }
    }
    out[idx] = num / den;
}

// ---------------------------------------------------------------------------
extern "C" void kernel_launch(void* const* d_in, const int* in_sizes, int n_in,
                              void* d_out, int out_size, void* d_ws, size_t ws_size,
                              hipStream_t stream) {
    const float* x       = (const float*)d_in[0];
    const float* w_off   = (const float*)d_in[1];
    const float* b_off   = (const float*)d_in[2];
    const float* w_align = (const float*)d_in[3];
    const float* b_align = (const float*)d_in[4];
    float* out = (float*)d_out;

    // workspace layout (~32.4 MB):
    char* p = (char*)d_ws;
    float* off  = (float*)p;                  p += (size_t)BB * 27 * HW * 4;  // 7.08 MB
    float* wten = (float*)p;                  p += (size_t)BB * CC * HW * 4;  // 16.78 MB
    unsigned short* xT  = (unsigned short*)p; p += (size_t)BB * HW * CC * 2;  // 8.39 MB
    unsigned short* wA2 = (unsigned short*)p; p += 32 * 576 * 2;              // 36.9 KB
    unsigned short* Wal2 = (unsigned short*)p;                                // 73.7 KB

    k_prep_tx<<<dim3(1240), dim3(256), 0, stream>>>(x, w_off, w_align, xT, wA2, Wal2);
    k_conv<<<dim3(1024), dim3(256), 0, stream>>>(xT, wA2, b_off, off);
    k_fused<<<dim3(1024), dim3(256), 0, stream>>>(xT, off, Wal2, b_align, wten);
    k_pool<<<dim3(4096), dim3(256), 0, stream>>>(x, wten, out);
}

// Round 4
// 112.882 us; speedup vs baseline: 1.2042x; 1.0368x over previous
//
#include <hip/hip_runtime.h>
#include <hip/hip_bf16.h>

#define HW 16384   // 128*128
#define CC 64
#define BB 4

typedef __attribute__((ext_vector_type(8))) short bf8;   // 8 bf16 (4 VGPRs)
typedef __attribute__((ext_vector_type(4))) float f4;    // MFMA C/D frag

static __device__ __forceinline__ float bf2f(unsigned short u) {
    return __uint_as_float(((unsigned)u) << 16);
}
static __device__ __forceinline__ unsigned short f2bf(float f) {
    __hip_bfloat16 h = __float2bfloat16(f);   // RNE
    return *reinterpret_cast<unsigned short*>(&h);
}

// ---------------------------------------------------------------------------
// K0: weight repack (blocks 0..215) + x transpose via LDS (blocks 216..1239).
//  wA2 : wave-coalesced A-frags for the conv phase. group g = tap*4+h2*2+m2,
//        lane l: wA2[(g*64+l)*8+j] = w_off[m2*16+(l&15)][h2*32+(l>>4)*8+j][tap]
//        (rows >=27 zero). 36,864 B.
//  Wal2: wave-coalesced A-frags for the align GEMM. g = (tap*2+h2)*4+mt:
//        Wal2[(g*64+l)*8+j] = w_align[mt*16+(l&15)][h2*32+(l>>4)*8+j][tap]
//  xT  [b*HW+hw][c] : channels contiguous (128B rows)
// ---------------------------------------------------------------------------
__global__ __launch_bounds__(256) void k_prep_tx(const float* __restrict__ x,
                                                 const float* __restrict__ w_off,
                                                 const float* __restrict__ w_align,
                                                 unsigned short* __restrict__ xT,
                                                 unsigned short* __restrict__ wA2,
                                                 unsigned short* __restrict__ Wal2) {
    __shared__ unsigned T32[64 * 33];   // 8448 B
    int bx = blockIdx.x, t = threadIdx.x;
    if (bx < 216) {
        int i = bx * 256 + t;
        if (i < 32 * 576) {             // 18432 elems -> wA2
            int jj = i & 7;
            int chunk = i >> 3;
            int l = chunk & 63;
            int g = chunk >> 6;         // 0..35 = tap*4 + h2*2 + m2
            int m2 = g & 1;
            int h2 = (g >> 1) & 1;
            int tp = g >> 2;            // tap 0..8
            int m = m2 * 16 + (l & 15);
            int c = h2 * 32 + (l >> 4) * 8 + jj;
            float v = (m < 27) ? w_off[m * 576 + c * 9 + tp] : 0.f;
            wA2[i] = f2bf(v);
        } else {
            int j = i - 32 * 576;       // 0..36863 = 72 groups x 64 lanes x 8
            int jj = j & 7;
            int chunk = j >> 3;
            int l = chunk & 63;
            int g = chunk >> 6;         // (tap*2+h2)*4 + mt
            int mt = g & 3;
            int th = g >> 2;
            int h2 = th & 1;
            int tp = th >> 1;           // tap 0..8
            int o = mt * 16 + (l & 15);
            int c = h2 * 32 + (l >> 4) * 8 + jj;
            Wal2[j] = f2bf(w_align[o * 576 + c * 9 + tp]);
        }
        return;
    }
    int pix0 = (bx - 216) * 64;
    int b = pix0 >> 14, hw0 = pix0 & (HW - 1);
    const float* xb = x + (size_t)b * CC * HW + hw0;
#pragma unroll
    for (int u = 0; u < 8; u++) {
        int i = t + 256 * u;                 // 2048 = 32 cp x 64 p
        int cp = i >> 6, p = i & 63;
        float v0 = xb[(size_t)(2 * cp) * HW + p];
        float v1 = xb[(size_t)(2 * cp + 1) * HW + p];
        T32[p * 33 + cp] = (unsigned)f2bf(v0) | ((unsigned)f2bf(v1) << 16);
    }
    __syncthreads();
#pragma unroll
    for (int u = 0; u < 2; u++) {
        int i = t + 256 * u;                 // 512 = 64 p x 8 q
        int p = i >> 3, q = i & 7;
        uint4 qq;
        qq.x = T32[p * 33 + q * 4 + 0];
        qq.y = T32[p * 33 + q * 4 + 1];
        qq.z = T32[p * 33 + q * 4 + 2];
        qq.w = T32[p * 33 + q * 4 + 3];
        *(uint4*)(xT + ((size_t)b * HW + hw0 + p) * CC + q * 8) = qq;
    }
}

// ---------------------------------------------------------------------------
// K1 (v5): FUSED offset-conv + bilinear + align GEMM. One 5x70 spatial tile
// (rows clamp(h-2..h+2), cols clamp(w0-3..w0+66), 44,800 B, chunk-XOR
// swizzled) serves BOTH the fixed-tap conv phase (rows h-1..h+1 always
// in-tile) and the bilinear gathers (~98% in-tile; exec-masked global
// fallback is bit-identical). The 27 per-pixel offset outputs are
// redistributed through a small padded LDS buffer OB (7,020 B) instead of a
// 14 MB off[] HBM round trip. LDS total 51,820 B -> 3 blocks/CU.
// Weights for both GEMMs via wave-coalesced VMEM (wA2/Wal2), off the
// critical path. Two barriers total.
// ---------------------------------------------------------------------------
__global__ __launch_bounds__(256, 3) void k_fused(const unsigned short* __restrict__ xT,
                                                  const unsigned short* __restrict__ wA2,
                                                  const unsigned short* __restrict__ Wal2,
                                                  const float* __restrict__ b_off,
                                                  const float* __restrict__ b_align,
                                                  float* __restrict__ wten) {
    __shared__ __align__(16) unsigned short TF[350 * 64];   // 5*70 entries * 128B
    __shared__ float OB[27 * 65];                           // pad 65: conflict-free

    int t = threadIdx.x, lane = t & 63, wv = t >> 6;
    int quad = lane >> 4, col = lane & 15;
    int pix0 = blockIdx.x * 64;
    int b = pix0 >> 14, hw0 = pix0 & (HW - 1);
    int h = hw0 >> 7, w0 = hw0 & 127;
    int pxo = wv * 16 + col;
    int px = hw0 + pxo, w = w0 + pxo;
    const unsigned short* xTb = xT + (size_t)b * HW * CC;
    const unsigned short* wl = Wal2 + lane * 8;        // + group*512 shorts

    // ---- stage 5x70 tile: 2800 16B chunks; source chunk pre-swizzled ----
#pragma unroll
    for (int u = 0; u < 11; u++) {
        int i = t + 256 * u;
        if (i < 2800) {
            int e = i >> 3, s = i & 7;
            int ty = e / 70, tx = e - ty * 70;
            int gy = min(max(h - 2 + ty, 0), 127);
            int gx = min(max(w0 - 3 + tx, 0), 127);
            int c = s ^ (e & 7);
            uint4 q = *(const uint4*)(xTb + ((size_t)((gy << 7) + gx)) * CC + c * 8);
            *(uint4*)(TF + i * 8) = q;
        }
    }
    __syncthreads();

    // ---- conv phase: 9 fixed taps, all in-tile (clamping commutes) ----
    {
        const bf8 zero = {0, 0, 0, 0, 0, 0, 0, 0};
        f4 a0 = {0.f, 0.f, 0.f, 0.f};
        f4 a1 = {0.f, 0.f, 0.f, 0.f};
#pragma unroll
        for (int tap = 0; tap < 9; tap++) {
            int dyt = tap / 3 - 1, dxt = tap - (tap / 3) * 3 - 1;
            int hs = h + dyt, ws = w + dxt;
            bool valid = ((unsigned)hs < 128u) && ((unsigned)ws < 128u);
            int e = (dyt + 2) * 70 + pxo + dxt + 3;   // tile row dyt+2, col pxo+dxt+3
            int sL = quad ^ (e & 7);
            bf8 b0 = *(const bf8*)(TF + e * 64 + (sL << 3));
            bf8 b1 = *(const bf8*)(TF + e * 64 + ((sL ^ 4) << 3));
            b0 = valid ? b0 : zero;
            b1 = valid ? b1 : zero;
            const bf8 a00 = *(const bf8*)(wA2 + (((tap * 4 + 0) * 64 + lane) << 3));
            const bf8 a01 = *(const bf8*)(wA2 + (((tap * 4 + 1) * 64 + lane) << 3));
            const bf8 a10 = *(const bf8*)(wA2 + (((tap * 4 + 2) * 64 + lane) << 3));
            const bf8 a11 = *(const bf8*)(wA2 + (((tap * 4 + 3) * 64 + lane) << 3));
            a0 = __builtin_amdgcn_mfma_f32_16x16x32_bf16(a00, b0, a0, 0, 0, 0);
            a1 = __builtin_amdgcn_mfma_f32_16x16x32_bf16(a01, b0, a1, 0, 0, 0);
            a0 = __builtin_amdgcn_mfma_f32_16x16x32_bf16(a10, b1, a0, 0, 0, 0);
            a1 = __builtin_amdgcn_mfma_f32_16x16x32_bf16(a11, b1, a1, 0, 0, 0);
        }
        // redistribute: outputs (o, pixel) -> OB[o][pxo]
#pragma unroll
        for (int i = 0; i < 4; i++) {
            int o0 = quad * 4 + i;                     // 0..15: never sigmoid
            OB[o0 * 65 + pxo] = a0[i] + b_off[o0];
            int o1 = 16 + o0;
            if (o1 < 27) {
                float v = a1[i] + b_off[o1];
                if (o1 >= 18) v = 2.f / (1.f + __expf(-v));
                OB[o1 * 65 + pxo] = v;
            }
        }
    }
    __syncthreads();

    // each lane pulls its pixel's 27 values (broadcast across quads, 16 banks)
    float dyv[9], dxv[9], mv[9];
#pragma unroll
    for (int k = 0; k < 9; k++) {
        dyv[k] = OB[(2 * k) * 65 + pxo];
        dxv[k] = OB[(2 * k + 1) * 65 + pxo];
        mv[k]  = OB[(18 + k) * 65 + pxo];
    }

    int hm2 = h - 2, hp2 = h + 2, wm3 = w0 - 3, wp66 = w0 + 66;

    f4 acc[4];
#pragma unroll
    for (int mt = 0; mt < 4; mt++) acc[mt] = (f4){0.f, 0.f, 0.f, 0.f};

#pragma unroll
    for (int k = 0; k < 9; k++) {
        float dy = dyv[k], dx = dxv[k], m = mv[k];
        int k3 = k / 3;
        float ys = (float)(h + k3 - 1) + dy;
        float xs = (float)(w + (k - 3 * k3) - 1) + dx;
        float y0f = floorf(ys), x0f = floorf(xs);
        float fy = ys - y0f, fx = xs - x0f;
        int y0 = (int)y0f, x0 = (int)x0f;
        int y1 = y0 + 1, x1 = x0 + 1;
        bool vy0 = (unsigned)y0 < 128u, vy1 = (unsigned)y1 < 128u;
        bool vx0 = (unsigned)x0 < 128u, vx1 = (unsigned)x1 < 128u;
        int cy0 = min(max(y0, 0), 127), cy1 = min(max(y1, 0), 127);
        int cx0 = min(max(x0, 0), 127), cx1 = min(max(x1, 0), 127);
        float w00 = (1.f - fy) * (1.f - fx) * ((vy0 && vx0) ? m : 0.f);
        float w01 = (1.f - fy) * fx         * ((vy0 && vx1) ? m : 0.f);
        float w10 = fy * (1.f - fx)         * ((vy1 && vx0) ? m : 0.f);
        float w11 = fy * fx                 * ((vy1 && vx1) ? m : 0.f);

        bool inT = (cy0 >= hm2) & (cy1 <= hp2) & (cx0 >= wm3) & (cx1 <= wp66);
        uint4 qa0, qa1, qa2, qa3, qb0, qb1, qb2, qb3;
        if (inT) {
            int r0 = (cy0 - hm2) * 70 - wm3, r1 = (cy1 - hm2) * 70 - wm3;
            int e00 = r0 + cx0, e01 = r0 + cx1, e10 = r1 + cx0, e11 = r1 + cx1;
            int s00 = quad ^ (e00 & 7), s01 = quad ^ (e01 & 7);
            int s10 = quad ^ (e10 & 7), s11 = quad ^ (e11 & 7);
            qa0 = *(const uint4*)(TF + e00 * 64 + (s00 << 3));
            qa1 = *(const uint4*)(TF + e01 * 64 + (s01 << 3));
            qa2 = *(const uint4*)(TF + e10 * 64 + (s10 << 3));
            qa3 = *(const uint4*)(TF + e11 * 64 + (s11 << 3));
            qb0 = *(const uint4*)(TF + e00 * 64 + ((s00 ^ 4) << 3));
            qb1 = *(const uint4*)(TF + e01 * 64 + ((s01 ^ 4) << 3));
            qb2 = *(const uint4*)(TF + e10 * 64 + ((s10 ^ 4) << 3));
            qb3 = *(const uint4*)(TF + e11 * 64 + ((s11 ^ 4) << 3));
        } else {
            const unsigned short* c00 = xTb + ((size_t)(cy0 * 128 + cx0)) * CC + quad * 8;
            const unsigned short* c01 = xTb + ((size_t)(cy0 * 128 + cx1)) * CC + quad * 8;
            const unsigned short* c10 = xTb + ((size_t)(cy1 * 128 + cx0)) * CC + quad * 8;
            const unsigned short* c11 = xTb + ((size_t)(cy1 * 128 + cx1)) * CC + quad * 8;
            qa0 = *(const uint4*)(c00);      qa1 = *(const uint4*)(c01);
            qa2 = *(const uint4*)(c10);      qa3 = *(const uint4*)(c11);
            qb0 = *(const uint4*)(c00 + 32); qb1 = *(const uint4*)(c01 + 32);
            qb2 = *(const uint4*)(c10 + 32); qb3 = *(const uint4*)(c11 + 32);
        }

        bf8 bfrag[2];
#pragma unroll
        for (int h2 = 0; h2 < 2; h2++) {
            const unsigned short* u00 = (const unsigned short*)(h2 ? &qb0 : &qa0);
            const unsigned short* u01 = (const unsigned short*)(h2 ? &qb1 : &qa1);
            const unsigned short* u10 = (const unsigned short*)(h2 ? &qb2 : &qa2);
            const unsigned short* u11 = (const unsigned short*)(h2 ? &qb3 : &qa3);
            unsigned short ov[8];
#pragma unroll
            for (int j = 0; j < 8; j++) {
                float v = w00 * bf2f(u00[j]) + w01 * bf2f(u01[j])
                        + w10 * bf2f(u10[j]) + w11 * bf2f(u11[j]);
                ov[j] = f2bf(v);
            }
            bfrag[h2] = *(const bf8*)ov;
        }
#pragma unroll
        for (int h2 = 0; h2 < 2; h2++) {
#pragma unroll
            for (int mt = 0; mt < 4; mt++) {
                const bf8 a = *(const bf8*)(wl + (size_t)(((k * 2 + h2) * 4 + mt) * 512));
                acc[mt] = __builtin_amdgcn_mfma_f32_16x16x32_bf16(a, bfrag[h2], acc[mt], 0, 0, 0);
            }
        }
    }

    // ---- epilogue: bias + exp(sigmoid) ----
    float* wb = wten + (size_t)b * CC * HW + px;
#pragma unroll
    for (int mt = 0; mt < 4; mt++)
#pragma unroll
        for (int i = 0; i < 4; i++) {
            int o = mt * 16 + quad * 4 + i;
            float u = acc[mt][i] + b_align[o];
            float sg = 1.f / (1.f + __expf(-u));
            wb[(size_t)o * HW] = __expf(sg);
        }
}

// ---------------------------------------------------------------------------
// K3: out = pool3s2(w*x)/pool3s2(w) (the /9 cancels; zero-pad taps drop out).
// ---------------------------------------------------------------------------
__global__ __launch_bounds__(256) void k_pool(const float* __restrict__ x,
                                              const float* __restrict__ wten,
                                              float* __restrict__ out) {
    int idx = blockIdx.x * 256 + threadIdx.x;
    int ow = idx & 63;
    int oh = (idx >> 6) & 63;
    int bc = idx >> 12;
    const float* wp = wten + (size_t)bc * HW;
    const float* xp = x + (size_t)bc * HW;
    float num = 0.f, den = 0.f;
#pragma unroll
    for (int iy = 0; iy < 3; iy++) {
        int y = 2 * oh + iy - 1;
        if ((unsigned)y >= 128u) continue;
#pragma unroll
        for (int ix = 0; ix < 3; ix++) {
            int xc = 2 * ow + ix - 1;
            if ((unsigned)xc >= 128u) continue;
            float wv = wp[y * 128 + xc];
            float xv = xp[y * 128 + xc];
            num = fmaf(wv, xv, num);
            den += wv;
        }
    }
    out[idx] = num / den;
}

// ---------------------------------------------------------------------------
extern "C" void kernel_launch(void* const* d_in, const int* in_sizes, int n_in,
                              void* d_out, int out_size, void* d_ws, size_t ws_size,
                              hipStream_t stream) {
    const float* x       = (const float*)d_in[0];
    const float* w_off   = (const float*)d_in[1];
    const float* b_off   = (const float*)d_in[2];
    const float* w_align = (const float*)d_in[3];
    const float* b_align = (const float*)d_in[4];
    float* out = (float*)d_out;

    // workspace layout (~25.3 MB):
    char* p = (char*)d_ws;
    float* wten = (float*)p;                  p += (size_t)BB * CC * HW * 4;  // 16.78 MB
    unsigned short* xT  = (unsigned short*)p; p += (size_t)BB * HW * CC * 2;  // 8.39 MB
    unsigned short* wA2 = (unsigned short*)p; p += 32 * 576 * 2;              // 36.9 KB
    unsigned short* Wal2 = (unsigned short*)p;                                // 73.7 KB

    k_prep_tx<<<dim3(1240), dim3(256), 0, stream>>>(x, w_off, w_align, xT, wA2, Wal2);
    k_fused<<<dim3(1024), dim3(256), 0, stream>>>(xT, wA2, Wal2, b_off, b_align, wten);
    k_pool<<<dim3(4096), dim3(256), 0, stream>>>(x, wten, out);
}

// Round 5
// 110.253 us; speedup vs baseline: 1.2329x; 1.0238x over previous
//
#include <hip/hip_runtime.h>
#include <hip/hip_bf16.h>

#define HW 16384   // 128*128
#define CC 64
#define BB 4

typedef __attribute__((ext_vector_type(8))) short bf8;   // 8 bf16 (4 VGPRs)
typedef __attribute__((ext_vector_type(4))) float f4;    // MFMA C/D frag

static __device__ __forceinline__ float bf2f(unsigned short u) {
    return __uint_as_float(((unsigned)u) << 16);
}
static __device__ __forceinline__ unsigned short f2bf(float f) {
    __hip_bfloat16 h = __float2bfloat16(f);   // RNE
    return *reinterpret_cast<unsigned short*>(&h);
}

// ---------------------------------------------------------------------------
// K0: weight repack (blocks 0..215) + x transpose via LDS (blocks 216..1239).
//  wA2 : wave-coalesced A-frags for the conv phase. group g = tap*4+h2*2+m2,
//        lane l: wA2[(g*64+l)*8+j] = w_off[m2*16+(l&15)][h2*32+(l>>4)*8+j][tap]
//        (rows >=27 zero). 36,864 B.
//  Wal2: wave-coalesced A-frags for the align GEMM. g = (tap*2+h2)*4+mt:
//        Wal2[(g*64+l)*8+j] = w_align[mt*16+(l&15)][h2*32+(l>>4)*8+j][tap]
//  xT  [b*HW+hw][c] : channels contiguous (128B rows)
// ---------------------------------------------------------------------------
__global__ __launch_bounds__(256) void k_prep_tx(const float* __restrict__ x,
                                                 const float* __restrict__ w_off,
                                                 const float* __restrict__ w_align,
                                                 unsigned short* __restrict__ xT,
                                                 unsigned short* __restrict__ wA2,
                                                 unsigned short* __restrict__ Wal2) {
    __shared__ unsigned T32[64 * 33];   // 8448 B
    int bx = blockIdx.x, t = threadIdx.x;
    if (bx < 216) {
        int i = bx * 256 + t;
        if (i < 32 * 576) {             // 18432 elems -> wA2
            int jj = i & 7;
            int chunk = i >> 3;
            int l = chunk & 63;
            int g = chunk >> 6;         // 0..35 = tap*4 + h2*2 + m2
            int m2 = g & 1;
            int h2 = (g >> 1) & 1;
            int tp = g >> 2;            // tap 0..8
            int m = m2 * 16 + (l & 15);
            int c = h2 * 32 + (l >> 4) * 8 + jj;
            float v = (m < 27) ? w_off[m * 576 + c * 9 + tp] : 0.f;
            wA2[i] = f2bf(v);
        } else {
            int j = i - 32 * 576;       // 0..36863 = 72 groups x 64 lanes x 8
            int jj = j & 7;
            int chunk = j >> 3;
            int l = chunk & 63;
            int g = chunk >> 6;         // (tap*2+h2)*4 + mt
            int mt = g & 3;
            int th = g >> 2;
            int h2 = th & 1;
            int tp = th >> 1;           // tap 0..8
            int o = mt * 16 + (l & 15);
            int c = h2 * 32 + (l >> 4) * 8 + jj;
            Wal2[j] = f2bf(w_align[o * 576 + c * 9 + tp]);
        }
        return;
    }
    int pix0 = (bx - 216) * 64;
    int b = pix0 >> 14, hw0 = pix0 & (HW - 1);
    const float* xb = x + (size_t)b * CC * HW + hw0;
#pragma unroll
    for (int u = 0; u < 8; u++) {
        int i = t + 256 * u;                 // 2048 = 32 cp x 64 p
        int cp = i >> 6, p = i & 63;
        float v0 = xb[(size_t)(2 * cp) * HW + p];
        float v1 = xb[(size_t)(2 * cp + 1) * HW + p];
        T32[p * 33 + cp] = (unsigned)f2bf(v0) | ((unsigned)f2bf(v1) << 16);
    }
    __syncthreads();
#pragma unroll
    for (int u = 0; u < 2; u++) {
        int i = t + 256 * u;                 // 512 = 64 p x 8 q
        int p = i >> 3, q = i & 7;
        uint4 qq;
        qq.x = T32[p * 33 + q * 4 + 0];
        qq.y = T32[p * 33 + q * 4 + 1];
        qq.z = T32[p * 33 + q * 4 + 2];
        qq.w = T32[p * 33 + q * 4 + 3];
        *(uint4*)(xT + ((size_t)b * HW + hw0 + p) * CC + q * 8) = qq;
    }
}

// ---------------------------------------------------------------------------
// K1 (v6): fused offset-conv + bilinear + align GEMM.
// Block = 512 threads = 8 waves = 128 pixels (2 stacked half-rows of 64:
// (h0,w0..w0+63) and (h0+1,...)). One 6x70 tile (rows clamp(h0-2..h0+3),
// cols clamp(w0-3..w0+66), 53,760 B, chunk-XOR swizzled) serves conv taps
// (always in-tile) and bilinear gathers (~98% in-tile; exec-masked global
// fallback is bit-identical). LDS 68,124 B -> EXACTLY 2 blocks/CU, grid 512
// -> zero tail, 16 waves/CU (4/SIMD). ONE barrier total: the offset
// redistribute through OB is intra-wave (each wave owns pxo columns
// wv*16..wv*16+15), so no post-conv sync -- waves run independently.
// OB pitch 133: quad write stride 532 % 32 = 20 -> conflict-free.
// ---------------------------------------------------------------------------
__global__ __launch_bounds__(512, 4) void k_fused(const unsigned short* __restrict__ xT,
                                                  const unsigned short* __restrict__ wA2,
                                                  const unsigned short* __restrict__ Wal2,
                                                  const float* __restrict__ b_off,
                                                  const float* __restrict__ b_align,
                                                  float* __restrict__ wten) {
    __shared__ __align__(16) unsigned short TF[420 * 64];   // 6*70 entries * 128B
    __shared__ float OB[27 * 133];                          // 14,364 B

    int t = threadIdx.x, lane = t & 63, wv = t >> 6;        // wv 0..7
    int quad = lane >> 4, col = lane & 15;
    int bx = blockIdx.x;
    int b = bx >> 7;                        // 128 blocks per batch image
    int r = bx & 127;
    int h0 = (r >> 1) * 2;                  // 0,2,...,126
    int w0 = (r & 1) * 64;
    int pxo = wv * 16 + col;                // 0..127
    int rr = pxo >> 6;                      // 0/1: which pixel row
    int hp = h0 + rr, wp = w0 + (pxo & 63);
    int px = (hp << 7) + wp;
    const unsigned short* xTb = xT + (size_t)b * HW * CC;
    const unsigned short* wl = Wal2 + lane * 8;        // + group*512 shorts

    // ---- stage 6x70 tile: 3360 16B chunks; source chunk pre-swizzled ----
#pragma unroll
    for (int u = 0; u < 7; u++) {
        int i = t + 512 * u;
        if (i < 3360) {
            int e = i >> 3, s = i & 7;
            int ty = e / 70, tx = e - ty * 70;
            int gy = min(max(h0 - 2 + ty, 0), 127);
            int gx = min(max(w0 - 3 + tx, 0), 127);
            int c = s ^ (e & 7);
            uint4 q = *(const uint4*)(xTb + ((size_t)((gy << 7) + gx)) * CC + c * 8);
            *(uint4*)(TF + i * 8) = q;
        }
    }
    __syncthreads();   // the ONLY barrier

    // ---- conv phase: 9 fixed taps, all in-tile (clamping commutes) ----
    {
        const bf8 zero = {0, 0, 0, 0, 0, 0, 0, 0};
        f4 a0 = {0.f, 0.f, 0.f, 0.f};
        f4 a1 = {0.f, 0.f, 0.f, 0.f};
#pragma unroll
        for (int tap = 0; tap < 9; tap++) {
            int dyt = tap / 3 - 1, dxt = tap - (tap / 3) * 3 - 1;
            int hs = hp + dyt, ws = wp + dxt;
            bool valid = ((unsigned)hs < 128u) && ((unsigned)ws < 128u);
            int e = (rr + dyt + 2) * 70 + (pxo & 63) + dxt + 3;   // tile entry
            int sL = quad ^ (e & 7);
            bf8 b0 = *(const bf8*)(TF + e * 64 + (sL << 3));
            bf8 b1 = *(const bf8*)(TF + e * 64 + ((sL ^ 4) << 3));
            b0 = valid ? b0 : zero;
            b1 = valid ? b1 : zero;
            const bf8 a00 = *(const bf8*)(wA2 + (((tap * 4 + 0) * 64 + lane) << 3));
            const bf8 a01 = *(const bf8*)(wA2 + (((tap * 4 + 1) * 64 + lane) << 3));
            const bf8 a10 = *(const bf8*)(wA2 + (((tap * 4 + 2) * 64 + lane) << 3));
            const bf8 a11 = *(const bf8*)(wA2 + (((tap * 4 + 3) * 64 + lane) << 3));
            a0 = __builtin_amdgcn_mfma_f32_16x16x32_bf16(a00, b0, a0, 0, 0, 0);
            a1 = __builtin_amdgcn_mfma_f32_16x16x32_bf16(a01, b0, a1, 0, 0, 0);
            a0 = __builtin_amdgcn_mfma_f32_16x16x32_bf16(a10, b1, a0, 0, 0, 0);
            a1 = __builtin_amdgcn_mfma_f32_16x16x32_bf16(a11, b1, a1, 0, 0, 0);
        }
        // redistribute (o, pixel) -> OB[o][pxo]; strictly intra-wave
#pragma unroll
        for (int i = 0; i < 4; i++) {
            int o0 = quad * 4 + i;                     // 0..15: never sigmoid
            OB[o0 * 133 + pxo] = a0[i] + b_off[o0];
            int o1 = 16 + o0;
            if (o1 < 27) {
                float v = a1[i] + b_off[o1];
                if (o1 >= 18) v = 2.f / (1.f + __expf(-v));
                OB[o1 * 133 + pxo] = v;
            }
        }
    }

    // each lane pulls its pixel's 27 values (16 banks, 4-way broadcast: free)
    float dyv[9], dxv[9], mv[9];
#pragma unroll
    for (int k = 0; k < 9; k++) {
        dyv[k] = OB[(2 * k) * 133 + pxo];
        dxv[k] = OB[(2 * k + 1) * 133 + pxo];
        mv[k]  = OB[(18 + k) * 133 + pxo];
    }

    int hm2 = h0 - 2, hp3 = h0 + 3, wm3 = w0 - 3, wp66 = w0 + 66;

    f4 acc[4];
#pragma unroll
    for (int mt = 0; mt < 4; mt++) acc[mt] = (f4){0.f, 0.f, 0.f, 0.f};

#pragma unroll
    for (int k = 0; k < 9; k++) {
        float dy = dyv[k], dx = dxv[k], m = mv[k];
        int k3 = k / 3;
        float ys = (float)(hp + k3 - 1) + dy;
        float xs = (float)(wp + (k - 3 * k3) - 1) + dx;
        float y0f = floorf(ys), x0f = floorf(xs);
        float fy = ys - y0f, fx = xs - x0f;
        int y0 = (int)y0f, x0 = (int)x0f;
        int y1 = y0 + 1, x1 = x0 + 1;
        bool vy0 = (unsigned)y0 < 128u, vy1 = (unsigned)y1 < 128u;
        bool vx0 = (unsigned)x0 < 128u, vx1 = (unsigned)x1 < 128u;
        int cy0 = min(max(y0, 0), 127), cy1 = min(max(y1, 0), 127);
        int cx0 = min(max(x0, 0), 127), cx1 = min(max(x1, 0), 127);
        float w00 = (1.f - fy) * (1.f - fx) * ((vy0 && vx0) ? m : 0.f);
        float w01 = (1.f - fy) * fx         * ((vy0 && vx1) ? m : 0.f);
        float w10 = fy * (1.f - fx)         * ((vy1 && vx0) ? m : 0.f);
        float w11 = fy * fx                 * ((vy1 && vx1) ? m : 0.f);

        bool inT = (cy0 >= hm2) & (cy1 <= hp3) & (cx0 >= wm3) & (cx1 <= wp66);
        uint4 qa0, qa1, qa2, qa3, qb0, qb1, qb2, qb3;
        if (inT) {
            int r0 = (cy0 - hm2) * 70 - wm3, r1 = (cy1 - hm2) * 70 - wm3;
            int e00 = r0 + cx0, e01 = r0 + cx1, e10 = r1 + cx0, e11 = r1 + cx1;
            int s00 = quad ^ (e00 & 7), s01 = quad ^ (e01 & 7);
            int s10 = quad ^ (e10 & 7), s11 = quad ^ (e11 & 7);
            qa0 = *(const uint4*)(TF + e00 * 64 + (s00 << 3));
            qa1 = *(const uint4*)(TF + e01 * 64 + (s01 << 3));
            qa2 = *(const uint4*)(TF + e10 * 64 + (s10 << 3));
            qa3 = *(const uint4*)(TF + e11 * 64 + (s11 << 3));
            qb0 = *(const uint4*)(TF + e00 * 64 + ((s00 ^ 4) << 3));
            qb1 = *(const uint4*)(TF + e01 * 64 + ((s01 ^ 4) << 3));
            qb2 = *(const uint4*)(TF + e10 * 64 + ((s10 ^ 4) << 3));
            qb3 = *(const uint4*)(TF + e11 * 64 + ((s11 ^ 4) << 3));
        } else {
            const unsigned short* c00 = xTb + ((size_t)(cy0 * 128 + cx0)) * CC + quad * 8;
            const unsigned short* c01 = xTb + ((size_t)(cy0 * 128 + cx1)) * CC + quad * 8;
            const unsigned short* c10 = xTb + ((size_t)(cy1 * 128 + cx0)) * CC + quad * 8;
            const unsigned short* c11 = xTb + ((size_t)(cy1 * 128 + cx1)) * CC + quad * 8;
            qa0 = *(const uint4*)(c00);      qa1 = *(const uint4*)(c01);
            qa2 = *(const uint4*)(c10);      qa3 = *(const uint4*)(c11);
            qb0 = *(const uint4*)(c00 + 32); qb1 = *(const uint4*)(c01 + 32);
            qb2 = *(const uint4*)(c10 + 32); qb3 = *(const uint4*)(c11 + 32);
        }

        bf8 bfrag[2];
#pragma unroll
        for (int h2 = 0; h2 < 2; h2++) {
            const unsigned short* u00 = (const unsigned short*)(h2 ? &qb0 : &qa0);
            const unsigned short* u01 = (const unsigned short*)(h2 ? &qb1 : &qa1);
            const unsigned short* u10 = (const unsigned short*)(h2 ? &qb2 : &qa2);
            const unsigned short* u11 = (const unsigned short*)(h2 ? &qb3 : &qa3);
            unsigned short ov[8];
#pragma unroll
            for (int j = 0; j < 8; j++) {
                float v = w00 * bf2f(u00[j]) + w01 * bf2f(u01[j])
                        + w10 * bf2f(u10[j]) + w11 * bf2f(u11[j]);
                ov[j] = f2bf(v);
            }
            bfrag[h2] = *(const bf8*)ov;
        }
#pragma unroll
        for (int h2 = 0; h2 < 2; h2++) {
#pragma unroll
            for (int mt = 0; mt < 4; mt++) {
                const bf8 a = *(const bf8*)(wl + (size_t)(((k * 2 + h2) * 4 + mt) * 512));
                acc[mt] = __builtin_amdgcn_mfma_f32_16x16x32_bf16(a, bfrag[h2], acc[mt], 0, 0, 0);
            }
        }
    }

    // ---- epilogue: bias + exp(sigmoid) ----
    float* wb = wten + (size_t)b * CC * HW + px;
#pragma unroll
    for (int mt = 0; mt < 4; mt++)
#pragma unroll
        for (int i = 0; i < 4; i++) {
            int o = mt * 16 + quad * 4 + i;
            float u = acc[mt][i] + b_align[o];
            float sg = 1.f / (1.f + __expf(-u));
            wb[(size_t)o * HW] = __expf(sg);
        }
}

// ---------------------------------------------------------------------------
// K3: out = pool3s2(w*x)/pool3s2(w) (the /9 cancels; zero-pad taps drop out).
// ---------------------------------------------------------------------------
__global__ __launch_bounds__(256) void k_pool(const float* __restrict__ x,
                                              const float* __restrict__ wten,
                                              float* __restrict__ out) {
    int idx = blockIdx.x * 256 + threadIdx.x;
    int ow = idx & 63;
    int oh = (idx >> 6) & 63;
    int bc = idx >> 12;
    const float* wp = wten + (size_t)bc * HW;
    const float* xp = x + (size_t)bc * HW;
    float num = 0.f, den = 0.f;
#pragma unroll
    for (int iy = 0; iy < 3; iy++) {
        int y = 2 * oh + iy - 1;
        if ((unsigned)y >= 128u) continue;
#pragma unroll
        for (int ix = 0; ix < 3; ix++) {
            int xc = 2 * ow + ix - 1;
            if ((unsigned)xc >= 128u) continue;
            float wv = wp[y * 128 + xc];
            float xv = xp[y * 128 + xc];
            num = fmaf(wv, xv, num);
            den += wv;
        }
    }
    out[idx] = num / den;
}

// ---------------------------------------------------------------------------
extern "C" void kernel_launch(void* const* d_in, const int* in_sizes, int n_in,
                              void* d_out, int out_size, void* d_ws, size_t ws_size,
                              hipStream_t stream) {
    const float* x       = (const float*)d_in[0];
    const float* w_off   = (const float*)d_in[1];
    const float* b_off   = (const float*)d_in[2];
    const float* w_align = (const float*)d_in[3];
    const float* b_align = (const float*)d_in[4];
    float* out = (float*)d_out;

    // workspace layout (~25.3 MB):
    char* p = (char*)d_ws;
    float* wten = (float*)p;                  p += (size_t)BB * CC * HW * 4;  // 16.78 MB
    unsigned short* xT  = (unsigned short*)p; p += (size_t)BB * HW * CC * 2;  // 8.39 MB
    unsigned short* wA2 = (unsigned short*)p; p += 32 * 576 * 2;              // 36.9 KB
    unsigned short* Wal2 = (unsigned short*)p;                                // 73.7 KB

    k_prep_tx<<<dim3(1240), dim3(256), 0, stream>>>(x, w_off, w_align, xT, wA2, Wal2);
    k_fused<<<dim3(512), dim3(512), 0, stream>>>(xT, wA2, Wal2, b_off, b_align, wten);
    k_pool<<<dim3(4096), dim3(256), 0, stream>>>(x, wten, out);
}